// Round 5
// baseline (183.542 us; speedup 1.0000x reference)
//
#include <hip/hip_runtime.h>

// Problem constants (from setup_inputs: DIM=96, C=32). dim is also passed as
// a device scalar, but the harness always uses DIM=96; sizes are hard-coded
// so the index maps fit a fixed workspace layout.
#define DIMC 96
#define VOX (DIMC * DIMC * DIMC)
#define C 32

typedef float f32x4 __attribute__((ext_vector_type(4)));

__device__ __forceinline__ int voxid(int x, int y, int z) {
    return (x * DIMC + y) * DIMC + z;
}

// Fused scatter: voxel -> last (max) point index for both point sets.
// atomicMax over indices reproduces the reference's serial last-writer-wins
// scatter semantics exactly (absmax 0.0 in rounds 2-3).
// 4 points per thread via int4 coord loads; also emits cvox[i] (current
// point i's voxel id) so the gather's first chain level is a single int load.
__global__ void scatter_idx_both(const int4* __restrict__ cc4,
                                 const int4* __restrict__ gc4,
                                 const int* __restrict__ cc,
                                 const int* __restrict__ gc,
                                 const int* __restrict__ origin,
                                 int nc, int ng,
                                 int* __restrict__ cmap,
                                 int* __restrict__ gmap,
                                 int* __restrict__ cvox) {
    const int nq_c = nc >> 2, nq_g = ng >> 2;
    int t = blockIdx.x * blockDim.x + threadIdx.x;

    if (t < nq_c) {
        // current quad: points 4t..4t+3, ints [12t,12t+12)
        int4 a = cc4[3 * t], b = cc4[3 * t + 1], c = cc4[3 * t + 2];
        int i = 4 * t;
        int v0 = voxid(a.x, a.y, a.z);
        int v1 = voxid(a.w, b.x, b.y);
        int v2 = voxid(b.z, b.w, c.x);
        int v3 = voxid(c.y, c.z, c.w);
        atomicMax(&cmap[v0], i);
        atomicMax(&cmap[v1], i + 1);
        atomicMax(&cmap[v2], i + 2);
        atomicMax(&cmap[v3], i + 3);
        *reinterpret_cast<int4*>(cvox + i) = make_int4(v0, v1, v2, v3);
    } else if (t - nq_c < nq_g) {
        // global quad
        int k4 = t - nq_c;
        int4 a = gc4[3 * k4], b = gc4[3 * k4 + 1], c = gc4[3 * k4 + 2];
        int ox = origin[0], oy = origin[1], oz = origin[2];
        int k = 4 * k4;
        int xs[4] = {a.x - ox, a.w - ox, b.z - ox, c.y - ox};
        int ys[4] = {a.y - oy, b.x - oy, b.w - oy, c.z - oy};
        int zs[4] = {a.z - oz, b.y - oz, c.x - oz, c.w - oz};
#pragma unroll
        for (int q = 0; q < 4; ++q) {
            if ((unsigned)xs[q] < (unsigned)DIMC &&
                (unsigned)ys[q] < (unsigned)DIMC &&
                (unsigned)zs[q] < (unsigned)DIMC) {
                atomicMax(&gmap[voxid(xs[q], ys[q], zs[q])], k + q);
            }
        }
    } else if (t == nq_c + nq_g) {
        // current tail (nc % 4 points)
        for (int i = nq_c * 4; i < nc; ++i) {
            int v = voxid(cc[3 * i], cc[3 * i + 1], cc[3 * i + 2]);
            atomicMax(&cmap[v], i);
            cvox[i] = v;
        }
    } else if (t == nq_c + nq_g + 1) {
        // global tail (ng % 4 points)
        int ox = origin[0], oy = origin[1], oz = origin[2];
        for (int k = nq_g * 4; k < ng; ++k) {
            int x = gc[3 * k] - ox, y = gc[3 * k + 1] - oy, z = gc[3 * k + 2] - oz;
            if ((unsigned)x < (unsigned)DIMC && (unsigned)y < (unsigned)DIMC &&
                (unsigned)z < (unsigned)DIMC)
                atomicMax(&gmap[voxid(x, y, z)], k);
        }
    }
}

// Gather: 16 lanes per point, 8 points per thread (8 independent
// cvox->map->row chains in flight to hide random-access latency).
// lanes 0..7  : x-part from current_values[cmap[v]]
// lanes 8..15 : h-part from global_values[gmap[v]] (or 0 if empty)
// One contiguous 256B row of out per point; nontemporal stores keep the
// streaming 67MB output from evicting the maps/value rows from L2.
__global__ __launch_bounds__(256) void gather_out_kernel(
    const f32x4* __restrict__ cur_vals,
    const f32x4* __restrict__ glob_vals,
    const int* __restrict__ cvox,
    const int* __restrict__ cmap,
    const int* __restrict__ gmap,
    int nc, f32x4* __restrict__ out) {
    const int lane = threadIdx.x & 15;      // float4 slot within 64-float row
    const int sub = threadIdx.x >> 4;       // 0..15: point-slot within block
    const int base = blockIdx.x * 128 + sub;  // 8 points: base + q*16
    const bool isx = lane < 8;
    const int* __restrict__ map = isx ? cmap : gmap;
    const f32x4* __restrict__ src = isx ? cur_vals : glob_vals;
    const int l = lane & 7;

    int p[8], v[8], j[8];
    f32x4 r[8];

#pragma unroll
    for (int q = 0; q < 8; ++q) p[q] = base + q * 16;
#pragma unroll
    for (int q = 0; q < 8; ++q) {
        int pp = p[q] < nc ? p[q] : 0;
        v[q] = cvox[pp];
    }
#pragma unroll
    for (int q = 0; q < 8; ++q) j[q] = map[v[q]];
#pragma unroll
    for (int q = 0; q < 8; ++q) {
        r[q] = (f32x4)(0.f);
        if (j[q] >= 0) r[q] = src[(size_t)j[q] * 8 + l];
    }
#pragma unroll
    for (int q = 0; q < 8; ++q) {
        if (p[q] < nc)
            __builtin_nontemporal_store(r[q], &out[(size_t)p[q] * 16 + lane]);
    }
}

extern "C" void kernel_launch(void* const* d_in, const int* in_sizes, int n_in,
                              void* d_out, int out_size, void* d_ws, size_t ws_size,
                              hipStream_t stream) {
    const f32x4* cur_vals = (const f32x4*)d_in[0];
    const f32x4* glob_vals = (const f32x4*)d_in[1];
    const int* cur_coords = (const int*)d_in[2];
    const int* glob_coords = (const int*)d_in[3];
    const int* rel_origin = (const int*)d_in[4];
    // d_in[5] = dim (device scalar, always 96 per setup_inputs)

    int nc = in_sizes[2] / 3;
    int ng = in_sizes[3] / 3;

    int* cmap = (int*)d_ws;
    int* gmap = cmap + VOX;
    int* cvox = gmap + VOX;

    // init both maps to -1 (0xFF per byte); cvox is fully written by scatter
    hipMemsetAsync(d_ws, 0xFF, (size_t)2 * VOX * sizeof(int), stream);

    const int B = 256;
    int nthreads = (nc >> 2) + (ng >> 2) + 2;  // quads + 2 tail handlers
    scatter_idx_both<<<(nthreads + B - 1) / B, B, 0, stream>>>(
        (const int4*)cur_coords, (const int4*)glob_coords,
        cur_coords, glob_coords, rel_origin, nc, ng, cmap, gmap, cvox);

    // 16 lanes/point, 8 points/thread -> 128 points per 256-thread block
    int blocks = (nc + 127) / 128;
    gather_out_kernel<<<blocks, B, 0, stream>>>(
        cur_vals, glob_vals, cvox, cmap, gmap, nc, (f32x4*)d_out);
}

// Round 6
// 164.424 us; speedup vs baseline: 1.1163x; 1.1163x over previous
//
#include <hip/hip_runtime.h>

// Problem constants (from setup_inputs: DIM=96, C=32). dim is also passed as
// a device scalar, but the harness always uses DIM=96; sizes are hard-coded
// so the index maps fit a fixed workspace layout.
#define DIMC 96
#define VOX (DIMC * DIMC * DIMC)
#define C 32

typedef float f32x4 __attribute__((ext_vector_type(4)));

__device__ __forceinline__ int voxid(int x, int y, int z) {
    return (x * DIMC + y) * DIMC + z;
}

// Fused scatter: voxel -> last (max) point index for both point sets.
// atomicMax over indices reproduces the reference's serial last-writer-wins
// scatter semantics exactly (absmax 0.0 in rounds 2-5).
// 4 points per thread via int4 coord loads; also emits cvox[i] (current
// point i's voxel id) so the gather's first chain level is a single int load.
__global__ void scatter_idx_both(const int4* __restrict__ cc4,
                                 const int4* __restrict__ gc4,
                                 const int* __restrict__ cc,
                                 const int* __restrict__ gc,
                                 const int* __restrict__ origin,
                                 int nc, int ng,
                                 int* __restrict__ cmap,
                                 int* __restrict__ gmap,
                                 int* __restrict__ cvox) {
    const int nq_c = nc >> 2, nq_g = ng >> 2;
    int t = blockIdx.x * blockDim.x + threadIdx.x;

    if (t < nq_c) {
        // current quad: points 4t..4t+3, ints [12t,12t+12)
        int4 a = cc4[3 * t], b = cc4[3 * t + 1], c = cc4[3 * t + 2];
        int i = 4 * t;
        int v0 = voxid(a.x, a.y, a.z);
        int v1 = voxid(a.w, b.x, b.y);
        int v2 = voxid(b.z, b.w, c.x);
        int v3 = voxid(c.y, c.z, c.w);
        atomicMax(&cmap[v0], i);
        atomicMax(&cmap[v1], i + 1);
        atomicMax(&cmap[v2], i + 2);
        atomicMax(&cmap[v3], i + 3);
        *reinterpret_cast<int4*>(cvox + i) = make_int4(v0, v1, v2, v3);
    } else if (t - nq_c < nq_g) {
        // global quad
        int k4 = t - nq_c;
        int4 a = gc4[3 * k4], b = gc4[3 * k4 + 1], c = gc4[3 * k4 + 2];
        int ox = origin[0], oy = origin[1], oz = origin[2];
        int k = 4 * k4;
        int xs[4] = {a.x - ox, a.w - ox, b.z - ox, c.y - ox};
        int ys[4] = {a.y - oy, b.x - oy, b.w - oy, c.z - oy};
        int zs[4] = {a.z - oz, b.y - oz, c.x - oz, c.w - oz};
#pragma unroll
        for (int q = 0; q < 4; ++q) {
            if ((unsigned)xs[q] < (unsigned)DIMC &&
                (unsigned)ys[q] < (unsigned)DIMC &&
                (unsigned)zs[q] < (unsigned)DIMC) {
                atomicMax(&gmap[voxid(xs[q], ys[q], zs[q])], k + q);
            }
        }
    } else if (t == nq_c + nq_g) {
        // current tail (nc % 4 points)
        for (int i = nq_c * 4; i < nc; ++i) {
            int v = voxid(cc[3 * i], cc[3 * i + 1], cc[3 * i + 2]);
            atomicMax(&cmap[v], i);
            cvox[i] = v;
        }
    } else if (t == nq_c + nq_g + 1) {
        // global tail (ng % 4 points)
        int ox = origin[0], oy = origin[1], oz = origin[2];
        for (int k = nq_g * 4; k < ng; ++k) {
            int x = gc[3 * k] - ox, y = gc[3 * k + 1] - oy, z = gc[3 * k + 2] - oz;
            if ((unsigned)x < (unsigned)DIMC && (unsigned)y < (unsigned)DIMC &&
                (unsigned)z < (unsigned)DIMC)
                atomicMax(&gmap[voxid(x, y, z)], k);
        }
    }
}

// Gather: 16 lanes per point, 4 points per thread. 4 pt/thread (not 8):
// round-5 showed 8pt costs VGPR 112 -> occupancy 17% and regresses; 4pt
// keeps VGPR ~64 so TLP stays high while 4 chains/thread are in flight.
// lanes 0..7  : x-part from current_values[cmap[v]]
// lanes 8..15 : h-part from global_values[gmap[v]] (or 0 if empty)
// Value rows are ~single-use: nontemporal LOADS keep the 8MB maps/cvox
// L2-resident (map lookup ~200cyc instead of ~900cyc). Nontemporal STORES
// keep the streaming 67MB output out of L2 for the same reason.
__global__ void gather_out_kernel(const f32x4* __restrict__ cur_vals,
                                  const f32x4* __restrict__ glob_vals,
                                  const int* __restrict__ cvox,
                                  const int* __restrict__ cmap,
                                  const int* __restrict__ gmap,
                                  int nc, f32x4* __restrict__ out) {
    const int lane = threadIdx.x & 15;       // float4 slot within 64-float row
    const int sub = threadIdx.x >> 4;        // 0..15: point-slot within block
    const int base = blockIdx.x * 64 + sub;  // 4 points: base + q*16
    const bool isx = lane < 8;
    const int* __restrict__ map = isx ? cmap : gmap;
    const f32x4* __restrict__ src = isx ? cur_vals : glob_vals;
    const int l = lane & 7;

    int p[4], v[4], j[4];
    f32x4 r[4];

#pragma unroll
    for (int q = 0; q < 4; ++q) p[q] = base + q * 16;
#pragma unroll
    for (int q = 0; q < 4; ++q) {
        int pp = p[q] < nc ? p[q] : 0;
        v[q] = cvox[pp];
    }
#pragma unroll
    for (int q = 0; q < 4; ++q) j[q] = map[v[q]];
#pragma unroll
    for (int q = 0; q < 4; ++q) {
        r[q] = (f32x4)(0.f);
        if (j[q] >= 0)
            r[q] = __builtin_nontemporal_load(&src[(size_t)j[q] * 8 + l]);
    }
#pragma unroll
    for (int q = 0; q < 4; ++q) {
        if (p[q] < nc)
            __builtin_nontemporal_store(r[q], &out[(size_t)p[q] * 16 + lane]);
    }
}

extern "C" void kernel_launch(void* const* d_in, const int* in_sizes, int n_in,
                              void* d_out, int out_size, void* d_ws, size_t ws_size,
                              hipStream_t stream) {
    const f32x4* cur_vals = (const f32x4*)d_in[0];
    const f32x4* glob_vals = (const f32x4*)d_in[1];
    const int* cur_coords = (const int*)d_in[2];
    const int* glob_coords = (const int*)d_in[3];
    const int* rel_origin = (const int*)d_in[4];
    // d_in[5] = dim (device scalar, always 96 per setup_inputs)

    int nc = in_sizes[2] / 3;
    int ng = in_sizes[3] / 3;

    int* cmap = (int*)d_ws;
    int* gmap = cmap + VOX;
    int* cvox = gmap + VOX;

    // init both maps to -1 (0xFF per byte); cvox is fully written by scatter
    hipMemsetAsync(d_ws, 0xFF, (size_t)2 * VOX * sizeof(int), stream);

    const int B = 256;
    int nthreads = (nc >> 2) + (ng >> 2) + 2;  // quads + 2 tail handlers
    scatter_idx_both<<<(nthreads + B - 1) / B, B, 0, stream>>>(
        (const int4*)cur_coords, (const int4*)glob_coords,
        cur_coords, glob_coords, rel_origin, nc, ng, cmap, gmap, cvox);

    // 16 lanes/point, 4 points/thread -> 64 points per 256-thread block
    int blocks = (nc + 63) / 64;
    gather_out_kernel<<<blocks, B, 0, stream>>>(
        cur_vals, glob_vals, cvox, cmap, gmap, nc, (f32x4*)d_out);
}